// Round 11
// baseline (398.880 us; speedup 1.0000x reference)
//
#include <hip/hip_runtime.h>
#include <hip/hip_bf16.h>
#include <math.h>

#define NNODES 50000
#define NEDGES 800000
#define CHUNKS (NEDGES / 32)     // 25000 chunks of 32 edges (original order)
#define NBLK 256
#define GWAVES (NBLK * 16)       // persistent waves

using short8 = __attribute__((ext_vector_type(8))) short;   // 8 bf16 = 4 VGPRs
using f32x4  = __attribute__((ext_vector_type(4))) float;
using f32x16 = __attribute__((ext_vector_type(16))) float;  // 32x32 MFMA acc
using u32x4  = __attribute__((ext_vector_type(4))) unsigned;

// fp32 -> bf16 RNE
__device__ __forceinline__ short f2b(float v) {
    return __builtin_bit_cast(short, __float2bfloat16(v));
}
// pack 2 fp32 -> 1 dword of 2 bf16 (lo = a)
__device__ __forceinline__ unsigned cvt2(float a, float b) {
    return (unsigned)(unsigned short)f2b(a) | ((unsigned)(unsigned short)f2b(b) << 16);
}

// ---- merged prep: x->bf16, W pack, CSR count ----
__global__ void prep_all(const float* __restrict__ x, short* __restrict__ xb,
                         const float* __restrict__ W1, const float* __restrict__ W2,
                         short* __restrict__ wpk, const int* __restrict__ ei,
                         unsigned* __restrict__ cnt)
{
    int b = blockIdx.x;
    if (b < 3125) {                       // x -> bf16 (800000 float4 groups)
        int i = b * 256 + threadIdx.x;
        float4 v = reinterpret_cast<const float4*>(x)[i];
        short4 o;
        o.x = f2b(v.x); o.y = f2b(v.y); o.z = f2b(v.z); o.w = f2b(v.w);
        reinterpret_cast<short4*>(xb)[i] = o;
    } else if (b < 6250) {                // CSR degree count
        int e = (b - 3125) * 256 + threadIdx.x;
        atomicAdd(&cnt[ei[e]], 1u);
    } else {                              // weight pack (32x32x16 A-frag order)
        int i = (b - 6250) * 256 + threadIdx.x;
        if (i < 40960) {                  // W1 [k<160][n<256]
            int k = i >> 8, n = i & 255;
            int lane = (n & 31) + (((k >> 3) & 1) << 5);
            wpk[(((n >> 5) * 10 + (k >> 4)) * 64 + lane) * 8 + (k & 7)] = f2b(W1[i]);
        }
        if (i < 16384) {                  // W2 [k<256][n<64]
            int k = i >> 6, n = i & 63;
            int lane = (n & 31) + (((k >> 3) & 1) << 5);
            wpk[40960 + (((n >> 5) * 16 + (k >> 4)) * 64 + lane) * 8 + (k & 7)] = f2b(W2[i]);
        }
    }
}

// ---- CSR scan/place (proven) ----
__global__ __launch_bounds__(1024)
void csr_scan1(const unsigned* __restrict__ cnt, unsigned* __restrict__ offs,
               unsigned* __restrict__ bsum) {
    __shared__ unsigned sbuf[1024];
    int t = threadIdx.x, i = blockIdx.x * 1024 + t;
    unsigned v = (i < NNODES) ? cnt[i] : 0u;
    sbuf[t] = v;
    __syncthreads();
    for (int off = 1; off < 1024; off <<= 1) {
        unsigned add = (t >= off) ? sbuf[t - off] : 0u;
        __syncthreads();
        sbuf[t] += add;
        __syncthreads();
    }
    if (i < NNODES) offs[i] = sbuf[t];
    if (t == 1023) bsum[blockIdx.x] = sbuf[1023];
}

__global__ void csr_scan2(unsigned* __restrict__ bsum) {
    int t = threadIdx.x;
    unsigned v = (t < 49) ? bsum[t] : 0u;
    unsigned orig = v;
    for (int off = 1; off < 64; off <<= 1) {
        unsigned n = __shfl_up(v, off, 64);
        if (t >= off) v += n;
    }
    if (t < 49) bsum[t] = v - orig;
}

__global__ __launch_bounds__(1024)
void csr_scan3(const unsigned* __restrict__ cnt, unsigned* __restrict__ offs,
               const unsigned* __restrict__ bsum) {
    int i = blockIdx.x * 1024 + threadIdx.x;
    if (i < NNODES)       offs[i] = offs[i] - cnt[i] + bsum[blockIdx.x];
    else if (i == NNODES) offs[i] = NEDGES;
}

__global__ void csr_place(const int* __restrict__ ei, const unsigned* __restrict__ offs,
                          unsigned* __restrict__ cur, unsigned* __restrict__ elist) {
    int e = blockIdx.x * 256 + threadIdx.x;
    if (e < NEDGES) {
        int r = ei[e];
        unsigned p = offs[r] + atomicAdd(&cur[r], 1u);
        elist[p] = (unsigned)e;
    }
}

// ---- main MLP: original-order chunks, 32x32x16 MFMA, permlane GEMM2 ----
// Split GEMM1 accumulator into 2 independent MFMA chains (latency ILP).
// STOREB16: also store bf16 shadow of out (same order) for the agg pass.
template<bool STOREB16>
__global__ __launch_bounds__(1024)
void edgeconv_main(const short* __restrict__ xb, const int* __restrict__ ei,
                   const float* __restrict__ ea, const short* __restrict__ wpk,
                   const float* __restrict__ b1, const float* __restrict__ b2,
                   float* __restrict__ outbuf, unsigned* __restrict__ ob16)
{
    __shared__ short wlds[57344];        // 112 KB: W1 frags (80K) + W2 frags (32K)

    for (int i = threadIdx.x; i < 7168; i += 1024)
        reinterpret_cast<short8*>(wlds)[i] = reinterpret_cast<const short8*>(wpk)[i];
    __syncthreads();                     // only block-wide barrier

    const short* w1s = wlds;
    const short* w2s = wlds + 40960;
    const int lane = threadIdx.x & 63;
    const int wave = threadIdx.x >> 6;
    const int l32 = lane & 31, hi = lane >> 5;
    const int gw = blockIdx.x * 16 + wave;

    // prime the index pipeline
    int r = 0, cc = 0;
    if (gw < CHUNKS) {
        int e0 = gw * 32 + l32;
        r  = ei[e0];
        cc = ei[NEDGES + e0];
    }

    for (int c = gw; c < CHUNKS; c += GWAVES) {
        const int e = c * 32 + l32;       // this chunk's edge (original order)

        // ---- prefetch next chunk's indices (coalesced, hidden under compute) ----
        int cn = c + GWAVES;
        int r_n = 0, cc_n = 0;
        if (cn < CHUNKS) {
            int e1 = cn * 32 + l32;
            r_n  = ei[e1];
            cc_n = ei[NEDGES + e1];
        }

        // ---- gather B-fragments: k = ks*16 + hi*8 + j ----
        short8 fx[10];
        #pragma unroll
        for (int ks = 0; ks < 4; ++ks)
            fx[ks] = *reinterpret_cast<const short8*>(xb + r * 64 + ks * 16 + hi * 8);
        #pragma unroll
        for (int ks = 0; ks < 4; ++ks)
            fx[4 + ks] = *reinterpret_cast<const short8*>(xb + cc * 64 + ks * 16 + hi * 8);
        #pragma unroll
        for (int ks = 0; ks < 2; ++ks) {
            const float4* p = reinterpret_cast<const float4*>(ea + (size_t)e * 32 + ks * 16 + hi * 8);
            float4 a = p[0], b = p[1];
            u32x4 uu;
            uu[0] = cvt2(a.x, a.y); uu[1] = cvt2(a.z, a.w);
            uu[2] = cvt2(b.x, b.y); uu[3] = cvt2(b.z, b.w);
            fx[8 + ks] = __builtin_bit_cast(short8, uu);
        }

        // ---- acc2 init = b2 ----
        f32x16 acc2[2];
        #pragma unroll
        for (int t2 = 0; t2 < 2; ++t2)
            #pragma unroll
            for (int g = 0; g < 4; ++g) {
                float4 bb = *reinterpret_cast<const float4*>(b2 + t2 * 32 + g * 8 + hi * 4);
                acc2[t2][g * 4 + 0] = bb.x; acc2[t2][g * 4 + 1] = bb.y;
                acc2[t2][g * 4 + 2] = bb.z; acc2[t2][g * 4 + 3] = bb.w;
            }

        #pragma unroll 1
        for (int t = 0; t < 8; ++t) {    // 8 H-tiles of 32 cols
            // ---- GEMM1: two independent MFMA chains (even/odd ks) ----
            f32x16 acc1, acc1b;
            #pragma unroll
            for (int g = 0; g < 4; ++g) {
                float4 bb = *reinterpret_cast<const float4*>(b1 + t * 32 + g * 8 + hi * 4);
                acc1[g * 4 + 0] = bb.x; acc1[g * 4 + 1] = bb.y;
                acc1[g * 4 + 2] = bb.z; acc1[g * 4 + 3] = bb.w;
                acc1b[g * 4 + 0] = 0.f; acc1b[g * 4 + 1] = 0.f;
                acc1b[g * 4 + 2] = 0.f; acc1b[g * 4 + 3] = 0.f;
            }
            #pragma unroll
            for (int ks = 0; ks < 10; ks += 2) {
                short8 wfa = *reinterpret_cast<const short8*>(
                    w1s + ((t * 10 + ks) * 64 + lane) * 8);
                short8 wfb = *reinterpret_cast<const short8*>(
                    w1s + ((t * 10 + ks + 1) * 64 + lane) * 8);
                acc1  = __builtin_amdgcn_mfma_f32_32x32x16_bf16(wfa, fx[ks],     acc1,  0, 0, 0);
                acc1b = __builtin_amdgcn_mfma_f32_32x32x16_bf16(wfb, fx[ks + 1], acc1b, 0, 0, 0);
            }
            acc1 = acc1 + acc1b;         // merge chains (16 v_add)

            // ---- ReLU + bf16 + permlane32_swap -> GEMM2 B-frags in-register ----
            #pragma unroll
            for (int ksl = 0; ksl < 2; ++ksl) {
                int q0 = ksl * 8;
                unsigned D0 = cvt2(fmaxf(acc1[q0 + 0], 0.f), fmaxf(acc1[q0 + 1], 0.f));
                unsigned D1 = cvt2(fmaxf(acc1[q0 + 2], 0.f), fmaxf(acc1[q0 + 3], 0.f));
                unsigned D2 = cvt2(fmaxf(acc1[q0 + 4], 0.f), fmaxf(acc1[q0 + 5], 0.f));
                unsigned D3 = cvt2(fmaxf(acc1[q0 + 6], 0.f), fmaxf(acc1[q0 + 7], 0.f));
                asm volatile("v_permlane32_swap_b32 %0, %1" : "+v"(D0), "+v"(D2));
                asm volatile("v_permlane32_swap_b32 %0, %1" : "+v"(D1), "+v"(D3));
                u32x4 bu; bu[0] = D0; bu[1] = D1; bu[2] = D2; bu[3] = D3;
                short8 hb = __builtin_bit_cast(short8, bu);

                int ks2 = t * 2 + ksl;
                short8 w20 = *reinterpret_cast<const short8*>(w2s + (ks2 * 64 + lane) * 8);
                short8 w21 = *reinterpret_cast<const short8*>(w2s + ((16 + ks2) * 64 + lane) * 8);
                acc2[0] = __builtin_amdgcn_mfma_f32_32x32x16_bf16(w20, hb, acc2[0], 0, 0, 0);
                acc2[1] = __builtin_amdgcn_mfma_f32_32x32x16_bf16(w21, hb, acc2[1], 0, 0, 0);
            }
        }

        // ---- epilogue: f32 out (nontemporal, write-only) + bf16 shadow (L3) ----
        #pragma unroll
        for (int t2 = 0; t2 < 2; ++t2)
            #pragma unroll
            for (int g = 0; g < 4; ++g) {
                f32x4 v;
                v[0] = acc2[t2][g * 4 + 0]; v[1] = acc2[t2][g * 4 + 1];
                v[2] = acc2[t2][g * 4 + 2]; v[3] = acc2[t2][g * 4 + 3];
                __builtin_nontemporal_store(v,
                    reinterpret_cast<f32x4*>(outbuf + (size_t)e * 64 + t2 * 32 + g * 8 + hi * 4));
                if (STOREB16) {
                    uint2 pk;
                    pk.x = cvt2(v[0], v[1]);
                    pk.y = cvt2(v[2], v[3]);
                    *reinterpret_cast<uint2*>(ob16 + (size_t)e * 32 + t2 * 16 + g * 4 + hi * 2) = pk;
                }
            }

        r = r_n; cc = cc_n;
    }
}

// ---- aggregate: half-wave per edge row, bf16 shadow reads (2 lines/row) ----
__global__ __launch_bounds__(256)
void agg_b16(const unsigned* __restrict__ offs, const unsigned* __restrict__ elist,
             const unsigned* __restrict__ ob16, float* __restrict__ agg)
{
    const int wave = threadIdx.x >> 6, lane = threadIdx.x & 63;
    const int l32 = lane & 31, half = lane >> 5;
    const int node = blockIdx.x * 4 + wave;
    if (node >= NNODES) return;
    const unsigned s = offs[node], eend = offs[node + 1];
    float m0 = -INFINITY, m1 = -INFINITY;
    for (unsigned p = s + half; p < eend; p += 2) {
        unsigned e = elist[p];
        unsigned u = ob16[(size_t)e * 32 + l32];           // cols 2*l32, 2*l32+1
        m0 = fmaxf(m0, __builtin_bit_cast(float, u << 16));
        m1 = fmaxf(m1, __builtin_bit_cast(float, u & 0xFFFF0000u));
    }
    m0 = fmaxf(m0, __shfl_xor(m0, 32, 64));
    m1 = fmaxf(m1, __shfl_xor(m1, 32, 64));
    if (half == 0) {
        float2 o;
        o.x = (s == eend) ? 0.0f : m0;
        o.y = (s == eend) ? 0.0f : m1;
        *reinterpret_cast<float2*>(agg + (size_t)node * 64 + l32 * 2) = o;
    }
}

// ---- fallback aggregate: random f32 reads (exact R8 semantics) ----
__global__ __launch_bounds__(256)
void agg_list(const unsigned* __restrict__ offs, const unsigned* __restrict__ elist,
              const float* __restrict__ outbuf, float* __restrict__ agg)
{
    const int wave = threadIdx.x >> 6, lane = threadIdx.x & 63;
    const int node = blockIdx.x * 4 + wave;
    if (node >= NNODES) return;
    const unsigned s = offs[node], eend = offs[node + 1];
    float m0 = -INFINITY, m1 = -INFINITY, m2 = -INFINITY, m3 = -INFINITY;
    unsigned p = s;
    for (; p + 4 <= eend; p += 4) {
        float a = outbuf[(size_t)elist[p + 0] * 64 + lane];
        float b = outbuf[(size_t)elist[p + 1] * 64 + lane];
        float c = outbuf[(size_t)elist[p + 2] * 64 + lane];
        float d = outbuf[(size_t)elist[p + 3] * 64 + lane];
        m0 = fmaxf(m0, a); m1 = fmaxf(m1, b);
        m2 = fmaxf(m2, c); m3 = fmaxf(m3, d);
    }
    for (; p < eend; ++p) m0 = fmaxf(m0, outbuf[(size_t)elist[p] * 64 + lane]);
    float m = fmaxf(fmaxf(m0, m1), fmaxf(m2, m3));
    agg[(size_t)node * 64 + lane] = (s == eend) ? 0.0f : m;
}

extern "C" void kernel_launch(void* const* d_in, const int* in_sizes, int n_in,
                              void* d_out, int out_size, void* d_ws, size_t ws_size,
                              hipStream_t stream)
{
    const float* x  = (const float*)d_in[0];
    const int*   ei = (const int*)d_in[1];
    const float* ea = (const float*)d_in[2];
    const float* W1 = (const float*)d_in[3];
    const float* b1 = (const float*)d_in[4];
    const float* W2 = (const float*)d_in[5];
    const float* b2 = (const float*)d_in[6];

    float* aggp = (float*)d_out;                          // [N,64]
    float* outp = aggp + (size_t)NNODES * 64;             // [E,64]

    // ws layout
    short*    xb   = (short*)d_ws;                        // 6,400,000 B bf16 x
    short*    wpk  = (short*)((char*)d_ws + 6400000);     //   114,688 B packed W1+W2
    unsigned* meta = (unsigned*)((char*)d_ws + 6514688);
    unsigned* cnt   = meta;                               // [50000]
    unsigned* cur   = meta + 50000;                       // [50000]
    unsigned* offs  = meta + 100000;                      // [50001]
    unsigned* bsum  = meta + 150016;                      // [49]
    unsigned* elist = meta + 150144;                      // [800000]  (ends 950144)
    unsigned* ob16  = meta + 950144;                      // [E,64] bf16 = 102.4 MB

    const size_t NEED = 6514688ULL + 950144ULL * 4ULL + 102400000ULL;  // ~112.7 MB
    const bool big = ws_size >= NEED;

    (void)hipMemsetAsync(cnt, 0, 100000 * sizeof(unsigned), stream);   // cnt + cur
    prep_all<<<6410, 256, 0, stream>>>(x, xb, W1, W2, wpk, ei, cnt);
    csr_scan1<<<49, 1024, 0, stream>>>(cnt, offs, bsum);
    csr_scan2<<<1, 64, 0, stream>>>(bsum);
    csr_scan3<<<49, 1024, 0, stream>>>(cnt, offs, bsum);
    csr_place<<<NEDGES / 256, 256, 0, stream>>>(ei, offs, cur, elist);
    if (big) {
        edgeconv_main<true><<<NBLK, 1024, 0, stream>>>(xb, ei, ea, wpk, b1, b2,
                                                       outp, ob16);
        agg_b16<<<(NNODES + 3) / 4, 256, 0, stream>>>(offs, elist, ob16, aggp);
    } else {
        edgeconv_main<false><<<NBLK, 1024, 0, stream>>>(xb, ei, ea, wpk, b1, b2,
                                                        outp, nullptr);
        agg_list<<<(NNODES + 3) / 4, 256, 0, stream>>>(offs, elist, outp, aggp);
    }
}

// Round 12
// 381.535 us; speedup vs baseline: 1.0455x; 1.0455x over previous
//
#include <hip/hip_runtime.h>
#include <hip/hip_bf16.h>
#include <math.h>

#define NNODES 50000
#define NEDGES 800000
#define CHUNKS (NEDGES / 32)     // 25000 chunks of 32 edges (original order)
#define NBLK 256
#define GWAVES (NBLK * 16)       // persistent waves

using short8 = __attribute__((ext_vector_type(8))) short;   // 8 bf16 = 4 VGPRs
using f32x4  = __attribute__((ext_vector_type(4))) float;
using f32x16 = __attribute__((ext_vector_type(16))) float;  // 32x32 MFMA acc
using u32x4  = __attribute__((ext_vector_type(4))) unsigned;

// fp32 -> bf16 RNE
__device__ __forceinline__ short f2b(float v) {
    return __builtin_bit_cast(short, __float2bfloat16(v));
}
// pack 2 fp32 -> 1 dword of 2 bf16 (lo = a)
__device__ __forceinline__ unsigned cvt2(float a, float b) {
    return (unsigned)(unsigned short)f2b(a) | ((unsigned)(unsigned short)f2b(b) << 16);
}
// unpack bf16 (lo/hi) -> f32
__device__ __forceinline__ float b2f_lo(unsigned u) {
    return __builtin_bit_cast(float, u << 16);
}
__device__ __forceinline__ float b2f_hi(unsigned u) {
    return __builtin_bit_cast(float, u & 0xFFFF0000u);
}

// ---- merged prep: x->bf16, W pack, CSR count ----
__global__ void prep_all(const float* __restrict__ x, short* __restrict__ xb,
                         const float* __restrict__ W1, const float* __restrict__ W2,
                         short* __restrict__ wpk, const int* __restrict__ ei,
                         unsigned* __restrict__ cnt)
{
    int b = blockIdx.x;
    if (b < 3125) {                       // x -> bf16 (800000 float4 groups)
        int i = b * 256 + threadIdx.x;
        float4 v = reinterpret_cast<const float4*>(x)[i];
        short4 o;
        o.x = f2b(v.x); o.y = f2b(v.y); o.z = f2b(v.z); o.w = f2b(v.w);
        reinterpret_cast<short4*>(xb)[i] = o;
    } else if (b < 6250) {                // CSR degree count
        int e = (b - 3125) * 256 + threadIdx.x;
        atomicAdd(&cnt[ei[e]], 1u);
    } else {                              // weight pack (32x32x16 A-frag order)
        int i = (b - 6250) * 256 + threadIdx.x;
        if (i < 40960) {                  // W1 [k<160][n<256]
            int k = i >> 8, n = i & 255;
            int lane = (n & 31) + (((k >> 3) & 1) << 5);
            wpk[(((n >> 5) * 10 + (k >> 4)) * 64 + lane) * 8 + (k & 7)] = f2b(W1[i]);
        }
        if (i < 16384) {                  // W2 [k<256][n<64]
            int k = i >> 6, n = i & 63;
            int lane = (n & 31) + (((k >> 3) & 1) << 5);
            wpk[40960 + (((n >> 5) * 16 + (k >> 4)) * 64 + lane) * 8 + (k & 7)] = f2b(W2[i]);
        }
    }
}

// ---- CSR scan/place (proven) ----
__global__ __launch_bounds__(1024)
void csr_scan1(const unsigned* __restrict__ cnt, unsigned* __restrict__ offs,
               unsigned* __restrict__ bsum) {
    __shared__ unsigned sbuf[1024];
    int t = threadIdx.x, i = blockIdx.x * 1024 + t;
    unsigned v = (i < NNODES) ? cnt[i] : 0u;
    sbuf[t] = v;
    __syncthreads();
    for (int off = 1; off < 1024; off <<= 1) {
        unsigned add = (t >= off) ? sbuf[t - off] : 0u;
        __syncthreads();
        sbuf[t] += add;
        __syncthreads();
    }
    if (i < NNODES) offs[i] = sbuf[t];
    if (t == 1023) bsum[blockIdx.x] = sbuf[1023];
}

__global__ void csr_scan2(unsigned* __restrict__ bsum) {
    int t = threadIdx.x;
    unsigned v = (t < 49) ? bsum[t] : 0u;
    unsigned orig = v;
    for (int off = 1; off < 64; off <<= 1) {
        unsigned n = __shfl_up(v, off, 64);
        if (t >= off) v += n;
    }
    if (t < 49) bsum[t] = v - orig;
}

__global__ __launch_bounds__(1024)
void csr_scan3(const unsigned* __restrict__ cnt, unsigned* __restrict__ offs,
               const unsigned* __restrict__ bsum) {
    int i = blockIdx.x * 1024 + threadIdx.x;
    if (i < NNODES)       offs[i] = offs[i] - cnt[i] + bsum[blockIdx.x];
    else if (i == NNODES) offs[i] = NEDGES;
}

__global__ void csr_place(const int* __restrict__ ei, const unsigned* __restrict__ offs,
                          unsigned* __restrict__ cur, unsigned* __restrict__ elist) {
    int e = blockIdx.x * 256 + threadIdx.x;
    if (e < NEDGES) {
        int r = ei[e];
        unsigned p = offs[r] + atomicAdd(&cur[r], 1u);
        elist[p] = (unsigned)e;
    }
}

// ---- main MLP: exact R8 structure (single acc1 chain) + bf16 shadow store ----
template<bool STOREB16>
__global__ __launch_bounds__(1024)
void edgeconv_main(const short* __restrict__ xb, const int* __restrict__ ei,
                   const float* __restrict__ ea, const short* __restrict__ wpk,
                   const float* __restrict__ b1, const float* __restrict__ b2,
                   float* __restrict__ outbuf, unsigned* __restrict__ ob16)
{
    __shared__ short wlds[57344];        // 112 KB: W1 frags (80K) + W2 frags (32K)

    for (int i = threadIdx.x; i < 7168; i += 1024)
        reinterpret_cast<short8*>(wlds)[i] = reinterpret_cast<const short8*>(wpk)[i];
    __syncthreads();                     // only block-wide barrier

    const short* w1s = wlds;
    const short* w2s = wlds + 40960;
    const int lane = threadIdx.x & 63;
    const int wave = threadIdx.x >> 6;
    const int l32 = lane & 31, hi = lane >> 5;
    const int gw = blockIdx.x * 16 + wave;

    // prime the index pipeline
    int r = 0, cc = 0;
    if (gw < CHUNKS) {
        int e0 = gw * 32 + l32;
        r  = ei[e0];
        cc = ei[NEDGES + e0];
    }

    for (int c = gw; c < CHUNKS; c += GWAVES) {
        const int e = c * 32 + l32;       // this chunk's edge (original order)

        // ---- prefetch next chunk's indices (coalesced, hidden under compute) ----
        int cn = c + GWAVES;
        int r_n = 0, cc_n = 0;
        if (cn < CHUNKS) {
            int e1 = cn * 32 + l32;
            r_n  = ei[e1];
            cc_n = ei[NEDGES + e1];
        }

        // ---- gather B-fragments: k = ks*16 + hi*8 + j ----
        short8 fx[10];
        #pragma unroll
        for (int ks = 0; ks < 4; ++ks)
            fx[ks] = *reinterpret_cast<const short8*>(xb + r * 64 + ks * 16 + hi * 8);
        #pragma unroll
        for (int ks = 0; ks < 4; ++ks)
            fx[4 + ks] = *reinterpret_cast<const short8*>(xb + cc * 64 + ks * 16 + hi * 8);
        #pragma unroll
        for (int ks = 0; ks < 2; ++ks) {
            const float4* p = reinterpret_cast<const float4*>(ea + (size_t)e * 32 + ks * 16 + hi * 8);
            float4 a = p[0], b = p[1];
            u32x4 uu;
            uu[0] = cvt2(a.x, a.y); uu[1] = cvt2(a.z, a.w);
            uu[2] = cvt2(b.x, b.y); uu[3] = cvt2(b.z, b.w);
            fx[8 + ks] = __builtin_bit_cast(short8, uu);
        }

        // ---- acc2 init = b2 ----
        f32x16 acc2[2];
        #pragma unroll
        for (int t2 = 0; t2 < 2; ++t2)
            #pragma unroll
            for (int g = 0; g < 4; ++g) {
                float4 bb = *reinterpret_cast<const float4*>(b2 + t2 * 32 + g * 8 + hi * 4);
                acc2[t2][g * 4 + 0] = bb.x; acc2[t2][g * 4 + 1] = bb.y;
                acc2[t2][g * 4 + 2] = bb.z; acc2[t2][g * 4 + 3] = bb.w;
            }

        #pragma unroll 1
        for (int t = 0; t < 8; ++t) {    // 8 H-tiles of 32 cols
            f32x16 acc1;
            #pragma unroll
            for (int g = 0; g < 4; ++g) {
                float4 bb = *reinterpret_cast<const float4*>(b1 + t * 32 + g * 8 + hi * 4);
                acc1[g * 4 + 0] = bb.x; acc1[g * 4 + 1] = bb.y;
                acc1[g * 4 + 2] = bb.z; acc1[g * 4 + 3] = bb.w;
            }
            #pragma unroll
            for (int ks = 0; ks < 10; ++ks) {
                short8 wf = *reinterpret_cast<const short8*>(
                    w1s + ((t * 10 + ks) * 64 + lane) * 8);
                acc1 = __builtin_amdgcn_mfma_f32_32x32x16_bf16(wf, fx[ks], acc1, 0, 0, 0);
            }
            // ---- ReLU + bf16 + permlane32_swap -> GEMM2 B-frags in-register ----
            #pragma unroll
            for (int ksl = 0; ksl < 2; ++ksl) {
                int q0 = ksl * 8;
                unsigned D0 = cvt2(fmaxf(acc1[q0 + 0], 0.f), fmaxf(acc1[q0 + 1], 0.f));
                unsigned D1 = cvt2(fmaxf(acc1[q0 + 2], 0.f), fmaxf(acc1[q0 + 3], 0.f));
                unsigned D2 = cvt2(fmaxf(acc1[q0 + 4], 0.f), fmaxf(acc1[q0 + 5], 0.f));
                unsigned D3 = cvt2(fmaxf(acc1[q0 + 6], 0.f), fmaxf(acc1[q0 + 7], 0.f));
                asm volatile("v_permlane32_swap_b32 %0, %1" : "+v"(D0), "+v"(D2));
                asm volatile("v_permlane32_swap_b32 %0, %1" : "+v"(D1), "+v"(D3));
                u32x4 bu; bu[0] = D0; bu[1] = D1; bu[2] = D2; bu[3] = D3;
                short8 hb = __builtin_bit_cast(short8, bu);

                int ks2 = t * 2 + ksl;
                short8 w20 = *reinterpret_cast<const short8*>(w2s + (ks2 * 64 + lane) * 8);
                short8 w21 = *reinterpret_cast<const short8*>(w2s + ((16 + ks2) * 64 + lane) * 8);
                acc2[0] = __builtin_amdgcn_mfma_f32_32x32x16_bf16(w20, hb, acc2[0], 0, 0, 0);
                acc2[1] = __builtin_amdgcn_mfma_f32_32x32x16_bf16(w21, hb, acc2[1], 0, 0, 0);
            }
        }

        // ---- epilogue: NT f32 out (write-only) + sequential bf16 shadow ----
        #pragma unroll
        for (int t2 = 0; t2 < 2; ++t2)
            #pragma unroll
            for (int g = 0; g < 4; ++g) {
                f32x4 v;
                v[0] = acc2[t2][g * 4 + 0]; v[1] = acc2[t2][g * 4 + 1];
                v[2] = acc2[t2][g * 4 + 2]; v[3] = acc2[t2][g * 4 + 3];
                __builtin_nontemporal_store(v,
                    reinterpret_cast<f32x4*>(outbuf + (size_t)e * 64 + t2 * 32 + g * 8 + hi * 4));
                if (STOREB16) {
                    uint2 pk;
                    pk.x = cvt2(v[0], v[1]);
                    pk.y = cvt2(v[2], v[3]);
                    *reinterpret_cast<uint2*>(ob16 + (size_t)e * 32 + t2 * 16 + g * 4 + hi * 2) = pk;
                }
            }

        r = r_n; cc = cc_n;
    }
}

// ---- aggregate: quarter-wave per edge row (4 rows in flight), bf16 reads ----
__global__ __launch_bounds__(256)
void agg_b16(const unsigned* __restrict__ offs, const unsigned* __restrict__ elist,
             const unsigned* __restrict__ ob16, float* __restrict__ agg)
{
    const int wave = threadIdx.x >> 6, lane = threadIdx.x & 63;
    const int l16 = lane & 15, qw = lane >> 4;   // quarter-wave 0..3
    const int node = blockIdx.x * 4 + wave;
    if (node >= NNODES) return;
    const unsigned s = offs[node], eend = offs[node + 1];
    float m0 = -INFINITY, m1 = -INFINITY, m2 = -INFINITY, m3 = -INFINITY;
    // qw handles rows s+qw, s+qw+4, ... ; 16 lanes x uint2 = full 128-B row
    for (unsigned p = s + qw; p < eend; p += 4) {
        unsigned e = elist[p];
        uint2 u = *reinterpret_cast<const uint2*>(ob16 + (size_t)e * 32 + l16 * 2);
        m0 = fmaxf(m0, b2f_lo(u.x)); m1 = fmaxf(m1, b2f_hi(u.x));
        m2 = fmaxf(m2, b2f_lo(u.y)); m3 = fmaxf(m3, b2f_hi(u.y));
    }
    // reduce the 4 quarter-wave partials (lanes with equal l16)
    m0 = fmaxf(m0, __shfl_xor(m0, 16, 64)); m1 = fmaxf(m1, __shfl_xor(m1, 16, 64));
    m2 = fmaxf(m2, __shfl_xor(m2, 16, 64)); m3 = fmaxf(m3, __shfl_xor(m3, 16, 64));
    m0 = fmaxf(m0, __shfl_xor(m0, 32, 64)); m1 = fmaxf(m1, __shfl_xor(m1, 32, 64));
    m2 = fmaxf(m2, __shfl_xor(m2, 32, 64)); m3 = fmaxf(m3, __shfl_xor(m3, 32, 64));
    if (qw == 0) {
        f32x4 o;
        bool emp = (s == eend);
        o[0] = emp ? 0.0f : m0; o[1] = emp ? 0.0f : m1;
        o[2] = emp ? 0.0f : m2; o[3] = emp ? 0.0f : m3;
        *reinterpret_cast<f32x4*>(agg + (size_t)node * 64 + l16 * 4) = o;
    }
}

// ---- fallback aggregate: random f32 reads (exact R8 semantics) ----
__global__ __launch_bounds__(256)
void agg_list(const unsigned* __restrict__ offs, const unsigned* __restrict__ elist,
              const float* __restrict__ outbuf, float* __restrict__ agg)
{
    const int wave = threadIdx.x >> 6, lane = threadIdx.x & 63;
    const int node = blockIdx.x * 4 + wave;
    if (node >= NNODES) return;
    const unsigned s = offs[node], eend = offs[node + 1];
    float m0 = -INFINITY, m1 = -INFINITY, m2 = -INFINITY, m3 = -INFINITY;
    unsigned p = s;
    for (; p + 4 <= eend; p += 4) {
        float a = outbuf[(size_t)elist[p + 0] * 64 + lane];
        float b = outbuf[(size_t)elist[p + 1] * 64 + lane];
        float c = outbuf[(size_t)elist[p + 2] * 64 + lane];
        float d = outbuf[(size_t)elist[p + 3] * 64 + lane];
        m0 = fmaxf(m0, a); m1 = fmaxf(m1, b);
        m2 = fmaxf(m2, c); m3 = fmaxf(m3, d);
    }
    for (; p < eend; ++p) m0 = fmaxf(m0, outbuf[(size_t)elist[p] * 64 + lane]);
    float m = fmaxf(fmaxf(m0, m1), fmaxf(m2, m3));
    agg[(size_t)node * 64 + lane] = (s == eend) ? 0.0f : m;
}

extern "C" void kernel_launch(void* const* d_in, const int* in_sizes, int n_in,
                              void* d_out, int out_size, void* d_ws, size_t ws_size,
                              hipStream_t stream)
{
    const float* x  = (const float*)d_in[0];
    const int*   ei = (const int*)d_in[1];
    const float* ea = (const float*)d_in[2];
    const float* W1 = (const float*)d_in[3];
    const float* b1 = (const float*)d_in[4];
    const float* W2 = (const float*)d_in[5];
    const float* b2 = (const float*)d_in[6];

    float* aggp = (float*)d_out;                          // [N,64]
    float* outp = aggp + (size_t)NNODES * 64;             // [E,64]

    // ws layout
    short*    xb   = (short*)d_ws;                        // 6,400,000 B bf16 x
    short*    wpk  = (short*)((char*)d_ws + 6400000);     //   114,688 B packed W1+W2
    unsigned* meta = (unsigned*)((char*)d_ws + 6514688);
    unsigned* cnt   = meta;                               // [50000]
    unsigned* cur   = meta + 50000;                       // [50000]
    unsigned* offs  = meta + 100000;                      // [50001]
    unsigned* bsum  = meta + 150016;                      // [49]
    unsigned* elist = meta + 150144;                      // [800000]  (ends 950144)
    unsigned* ob16  = meta + 950144;                      // [E,64] bf16 = 102.4 MB

    const size_t NEED = 6514688ULL + 950144ULL * 4ULL + 102400000ULL;  // ~112.7 MB
    const bool big = ws_size >= NEED;

    (void)hipMemsetAsync(cnt, 0, 100000 * sizeof(unsigned), stream);   // cnt + cur
    prep_all<<<6410, 256, 0, stream>>>(x, xb, W1, W2, wpk, ei, cnt);
    csr_scan1<<<49, 1024, 0, stream>>>(cnt, offs, bsum);
    csr_scan2<<<1, 64, 0, stream>>>(bsum);
    csr_scan3<<<49, 1024, 0, stream>>>(cnt, offs, bsum);
    csr_place<<<NEDGES / 256, 256, 0, stream>>>(ei, offs, cur, elist);
    if (big) {
        edgeconv_main<true><<<NBLK, 1024, 0, stream>>>(xb, ei, ea, wpk, b1, b2,
                                                       outp, ob16);
        agg_b16<<<(NNODES + 3) / 4, 256, 0, stream>>>(offs, elist, ob16, aggp);
    } else {
        edgeconv_main<false><<<NBLK, 1024, 0, stream>>>(xb, ei, ea, wpk, b1, b2,
                                                        outp, nullptr);
        agg_list<<<(NNODES + 3) / 4, 256, 0, stream>>>(offs, elist, outp, aggp);
    }
}

// Round 13
// 358.355 us; speedup vs baseline: 1.1131x; 1.0647x over previous
//
#include <hip/hip_runtime.h>
#include <hip/hip_bf16.h>
#include <math.h>

#define NNODES 50000
#define NEDGES 800000
#define CHUNKS (NEDGES / 32)     // 25000 chunks of 32 edges (original order)
#define NBLK 256
#define GWAVES (NBLK * 16)       // persistent waves

using short8 = __attribute__((ext_vector_type(8))) short;   // 8 bf16 = 4 VGPRs
using f32x4  = __attribute__((ext_vector_type(4))) float;
using f32x16 = __attribute__((ext_vector_type(16))) float;  // 32x32 MFMA acc
using u32x4  = __attribute__((ext_vector_type(4))) unsigned;

// fp32 -> bf16 RNE
__device__ __forceinline__ short f2b(float v) {
    return __builtin_bit_cast(short, __float2bfloat16(v));
}
// pack 2 fp32 -> 1 dword of 2 bf16 (lo = a)
__device__ __forceinline__ unsigned cvt2(float a, float b) {
    return (unsigned)(unsigned short)f2b(a) | ((unsigned)(unsigned short)f2b(b) << 16);
}
// unpack bf16 (lo/hi) -> f32
__device__ __forceinline__ float b2f_lo(unsigned u) {
    return __builtin_bit_cast(float, u << 16);
}
__device__ __forceinline__ float b2f_hi(unsigned u) {
    return __builtin_bit_cast(float, u & 0xFFFF0000u);
}

// ---- merged prep: x->bf16, W pack, CSR count ----
__global__ void prep_all(const float* __restrict__ x, short* __restrict__ xb,
                         const float* __restrict__ W1, const float* __restrict__ W2,
                         short* __restrict__ wpk, const int* __restrict__ ei,
                         unsigned* __restrict__ cnt)
{
    int b = blockIdx.x;
    if (b < 3125) {                       // x -> bf16 (800000 float4 groups)
        int i = b * 256 + threadIdx.x;
        float4 v = reinterpret_cast<const float4*>(x)[i];
        short4 o;
        o.x = f2b(v.x); o.y = f2b(v.y); o.z = f2b(v.z); o.w = f2b(v.w);
        reinterpret_cast<short4*>(xb)[i] = o;
    } else if (b < 6250) {                // CSR degree count
        int e = (b - 3125) * 256 + threadIdx.x;
        atomicAdd(&cnt[ei[e]], 1u);
    } else {                              // weight pack (32x32x16 A-frag order)
        int i = (b - 6250) * 256 + threadIdx.x;
        if (i < 40960) {                  // W1 [k<160][n<256]
            int k = i >> 8, n = i & 255;
            int lane = (n & 31) + (((k >> 3) & 1) << 5);
            wpk[(((n >> 5) * 10 + (k >> 4)) * 64 + lane) * 8 + (k & 7)] = f2b(W1[i]);
        }
        if (i < 16384) {                  // W2 [k<256][n<64]
            int k = i >> 6, n = i & 63;
            int lane = (n & 31) + (((k >> 3) & 1) << 5);
            wpk[40960 + (((n >> 5) * 16 + (k >> 4)) * 64 + lane) * 8 + (k & 7)] = f2b(W2[i]);
        }
    }
}

// ---- CSR scan/place (proven) ----
__global__ __launch_bounds__(1024)
void csr_scan1(const unsigned* __restrict__ cnt, unsigned* __restrict__ offs,
               unsigned* __restrict__ bsum) {
    __shared__ unsigned sbuf[1024];
    int t = threadIdx.x, i = blockIdx.x * 1024 + t;
    unsigned v = (i < NNODES) ? cnt[i] : 0u;
    sbuf[t] = v;
    __syncthreads();
    for (int off = 1; off < 1024; off <<= 1) {
        unsigned add = (t >= off) ? sbuf[t - off] : 0u;
        __syncthreads();
        sbuf[t] += add;
        __syncthreads();
    }
    if (i < NNODES) offs[i] = sbuf[t];
    if (t == 1023) bsum[blockIdx.x] = sbuf[1023];
}

__global__ void csr_scan2(unsigned* __restrict__ bsum) {
    int t = threadIdx.x;
    unsigned v = (t < 49) ? bsum[t] : 0u;
    unsigned orig = v;
    for (int off = 1; off < 64; off <<= 1) {
        unsigned n = __shfl_up(v, off, 64);
        if (t >= off) v += n;
    }
    if (t < 49) bsum[t] = v - orig;
}

__global__ __launch_bounds__(1024)
void csr_scan3(const unsigned* __restrict__ cnt, unsigned* __restrict__ offs,
               const unsigned* __restrict__ bsum) {
    int i = blockIdx.x * 1024 + threadIdx.x;
    if (i < NNODES)       offs[i] = offs[i] - cnt[i] + bsum[blockIdx.x];
    else if (i == NNODES) offs[i] = NEDGES;
}

__global__ void csr_place(const int* __restrict__ ei, const unsigned* __restrict__ offs,
                          unsigned* __restrict__ cur, unsigned* __restrict__ elist) {
    int e = blockIdx.x * 256 + threadIdx.x;
    if (e < NEDGES) {
        int r = ei[e];
        unsigned p = offs[r] + atomicAdd(&cur[r], 1u);
        elist[p] = (unsigned)e;
    }
}

// ---- main MLP: R8 structure + bf16 shadow store (normal stores, L2-merged) ----
template<bool STOREB16>
__global__ __launch_bounds__(1024)
void edgeconv_main(const short* __restrict__ xb, const int* __restrict__ ei,
                   const float* __restrict__ ea, const short* __restrict__ wpk,
                   const float* __restrict__ b1, const float* __restrict__ b2,
                   float* __restrict__ outbuf, unsigned* __restrict__ ob16)
{
    __shared__ short wlds[57344];        // 112 KB: W1 frags (80K) + W2 frags (32K)

    for (int i = threadIdx.x; i < 7168; i += 1024)
        reinterpret_cast<short8*>(wlds)[i] = reinterpret_cast<const short8*>(wpk)[i];
    __syncthreads();                     // only block-wide barrier

    const short* w1s = wlds;
    const short* w2s = wlds + 40960;
    const int lane = threadIdx.x & 63;
    const int wave = threadIdx.x >> 6;
    const int l32 = lane & 31, hi = lane >> 5;
    const int gw = blockIdx.x * 16 + wave;

    // prime the index pipeline
    int r = 0, cc = 0;
    if (gw < CHUNKS) {
        int e0 = gw * 32 + l32;
        r  = ei[e0];
        cc = ei[NEDGES + e0];
    }

    for (int c = gw; c < CHUNKS; c += GWAVES) {
        const int e = c * 32 + l32;       // this chunk's edge (original order)

        // ---- prefetch next chunk's indices (coalesced, hidden under compute) ----
        int cn = c + GWAVES;
        int r_n = 0, cc_n = 0;
        if (cn < CHUNKS) {
            int e1 = cn * 32 + l32;
            r_n  = ei[e1];
            cc_n = ei[NEDGES + e1];
        }

        // ---- gather B-fragments: k = ks*16 + hi*8 + j ----
        short8 fx[10];
        #pragma unroll
        for (int ks = 0; ks < 4; ++ks)
            fx[ks] = *reinterpret_cast<const short8*>(xb + r * 64 + ks * 16 + hi * 8);
        #pragma unroll
        for (int ks = 0; ks < 4; ++ks)
            fx[4 + ks] = *reinterpret_cast<const short8*>(xb + cc * 64 + ks * 16 + hi * 8);
        #pragma unroll
        for (int ks = 0; ks < 2; ++ks) {
            const float4* p = reinterpret_cast<const float4*>(ea + (size_t)e * 32 + ks * 16 + hi * 8);
            float4 a = p[0], b = p[1];
            u32x4 uu;
            uu[0] = cvt2(a.x, a.y); uu[1] = cvt2(a.z, a.w);
            uu[2] = cvt2(b.x, b.y); uu[3] = cvt2(b.z, b.w);
            fx[8 + ks] = __builtin_bit_cast(short8, uu);
        }

        // ---- acc2 init = b2 ----
        f32x16 acc2[2];
        #pragma unroll
        for (int t2 = 0; t2 < 2; ++t2)
            #pragma unroll
            for (int g = 0; g < 4; ++g) {
                float4 bb = *reinterpret_cast<const float4*>(b2 + t2 * 32 + g * 8 + hi * 4);
                acc2[t2][g * 4 + 0] = bb.x; acc2[t2][g * 4 + 1] = bb.y;
                acc2[t2][g * 4 + 2] = bb.z; acc2[t2][g * 4 + 3] = bb.w;
            }

        #pragma unroll 1
        for (int t = 0; t < 8; ++t) {    // 8 H-tiles of 32 cols
            f32x16 acc1;
            #pragma unroll
            for (int g = 0; g < 4; ++g) {
                float4 bb = *reinterpret_cast<const float4*>(b1 + t * 32 + g * 8 + hi * 4);
                acc1[g * 4 + 0] = bb.x; acc1[g * 4 + 1] = bb.y;
                acc1[g * 4 + 2] = bb.z; acc1[g * 4 + 3] = bb.w;
            }
            #pragma unroll
            for (int ks = 0; ks < 10; ++ks) {
                short8 wf = *reinterpret_cast<const short8*>(
                    w1s + ((t * 10 + ks) * 64 + lane) * 8);
                acc1 = __builtin_amdgcn_mfma_f32_32x32x16_bf16(wf, fx[ks], acc1, 0, 0, 0);
            }
            // ---- ReLU + bf16 + permlane32_swap -> GEMM2 B-frags in-register ----
            #pragma unroll
            for (int ksl = 0; ksl < 2; ++ksl) {
                int q0 = ksl * 8;
                unsigned D0 = cvt2(fmaxf(acc1[q0 + 0], 0.f), fmaxf(acc1[q0 + 1], 0.f));
                unsigned D1 = cvt2(fmaxf(acc1[q0 + 2], 0.f), fmaxf(acc1[q0 + 3], 0.f));
                unsigned D2 = cvt2(fmaxf(acc1[q0 + 4], 0.f), fmaxf(acc1[q0 + 5], 0.f));
                unsigned D3 = cvt2(fmaxf(acc1[q0 + 6], 0.f), fmaxf(acc1[q0 + 7], 0.f));
                asm volatile("v_permlane32_swap_b32 %0, %1" : "+v"(D0), "+v"(D2));
                asm volatile("v_permlane32_swap_b32 %0, %1" : "+v"(D1), "+v"(D3));
                u32x4 bu; bu[0] = D0; bu[1] = D1; bu[2] = D2; bu[3] = D3;
                short8 hb = __builtin_bit_cast(short8, bu);

                int ks2 = t * 2 + ksl;
                short8 w20 = *reinterpret_cast<const short8*>(w2s + (ks2 * 64 + lane) * 8);
                short8 w21 = *reinterpret_cast<const short8*>(w2s + ((16 + ks2) * 64 + lane) * 8);
                acc2[0] = __builtin_amdgcn_mfma_f32_32x32x16_bf16(w20, hb, acc2[0], 0, 0, 0);
                acc2[1] = __builtin_amdgcn_mfma_f32_32x32x16_bf16(w21, hb, acc2[1], 0, 0, 0);
            }
        }

        // ---- epilogue: normal f32 out stores (L2-merged) + bf16 shadow ----
        #pragma unroll
        for (int t2 = 0; t2 < 2; ++t2)
            #pragma unroll
            for (int g = 0; g < 4; ++g) {
                f32x4 v;
                v[0] = acc2[t2][g * 4 + 0]; v[1] = acc2[t2][g * 4 + 1];
                v[2] = acc2[t2][g * 4 + 2]; v[3] = acc2[t2][g * 4 + 3];
                *reinterpret_cast<f32x4*>(outbuf + (size_t)e * 64 + t2 * 32 + g * 8 + hi * 4) = v;
                if (STOREB16) {
                    uint2 pk;
                    pk.x = cvt2(v[0], v[1]);
                    pk.y = cvt2(v[2], v[3]);
                    *reinterpret_cast<uint2*>(ob16 + (size_t)e * 32 + t2 * 16 + g * 4 + hi * 2) = pk;
                }
            }

        r = r_n; cc = cc_n;
    }
}

// ---- aggregate: quarter-wave per edge row (4 rows in flight), bf16 reads ----
__global__ __launch_bounds__(256)
void agg_b16(const unsigned* __restrict__ offs, const unsigned* __restrict__ elist,
             const unsigned* __restrict__ ob16, float* __restrict__ agg)
{
    const int wave = threadIdx.x >> 6, lane = threadIdx.x & 63;
    const int l16 = lane & 15, qw = lane >> 4;   // quarter-wave 0..3
    const int node = blockIdx.x * 4 + wave;
    if (node >= NNODES) return;
    const unsigned s = offs[node], eend = offs[node + 1];
    float m0 = -INFINITY, m1 = -INFINITY, m2 = -INFINITY, m3 = -INFINITY;
    // qw handles rows s+qw, s+qw+4, ... ; 16 lanes x uint2 = full 128-B row
    for (unsigned p = s + qw; p < eend; p += 4) {
        unsigned e = elist[p];
        uint2 u = *reinterpret_cast<const uint2*>(ob16 + (size_t)e * 32 + l16 * 2);
        m0 = fmaxf(m0, b2f_lo(u.x)); m1 = fmaxf(m1, b2f_hi(u.x));
        m2 = fmaxf(m2, b2f_lo(u.y)); m3 = fmaxf(m3, b2f_hi(u.y));
    }
    // reduce the 4 quarter-wave partials (lanes with equal l16)
    m0 = fmaxf(m0, __shfl_xor(m0, 16, 64)); m1 = fmaxf(m1, __shfl_xor(m1, 16, 64));
    m2 = fmaxf(m2, __shfl_xor(m2, 16, 64)); m3 = fmaxf(m3, __shfl_xor(m3, 16, 64));
    m0 = fmaxf(m0, __shfl_xor(m0, 32, 64)); m1 = fmaxf(m1, __shfl_xor(m1, 32, 64));
    m2 = fmaxf(m2, __shfl_xor(m2, 32, 64)); m3 = fmaxf(m3, __shfl_xor(m3, 32, 64));
    if (qw == 0) {
        f32x4 o;
        bool emp = (s == eend);
        o[0] = emp ? 0.0f : m0; o[1] = emp ? 0.0f : m1;
        o[2] = emp ? 0.0f : m2; o[3] = emp ? 0.0f : m3;
        *reinterpret_cast<f32x4*>(agg + (size_t)node * 64 + l16 * 4) = o;
    }
}

// ---- fallback aggregate: random f32 reads (exact R8 semantics) ----
__global__ __launch_bounds__(256)
void agg_list(const unsigned* __restrict__ offs, const unsigned* __restrict__ elist,
              const float* __restrict__ outbuf, float* __restrict__ agg)
{
    const int wave = threadIdx.x >> 6, lane = threadIdx.x & 63;
    const int node = blockIdx.x * 4 + wave;
    if (node >= NNODES) return;
    const unsigned s = offs[node], eend = offs[node + 1];
    float m0 = -INFINITY, m1 = -INFINITY, m2 = -INFINITY, m3 = -INFINITY;
    unsigned p = s;
    for (; p + 4 <= eend; p += 4) {
        float a = outbuf[(size_t)elist[p + 0] * 64 + lane];
        float b = outbuf[(size_t)elist[p + 1] * 64 + lane];
        float c = outbuf[(size_t)elist[p + 2] * 64 + lane];
        float d = outbuf[(size_t)elist[p + 3] * 64 + lane];
        m0 = fmaxf(m0, a); m1 = fmaxf(m1, b);
        m2 = fmaxf(m2, c); m3 = fmaxf(m3, d);
    }
    for (; p < eend; ++p) m0 = fmaxf(m0, outbuf[(size_t)elist[p] * 64 + lane]);
    float m = fmaxf(fmaxf(m0, m1), fmaxf(m2, m3));
    agg[(size_t)node * 64 + lane] = (s == eend) ? 0.0f : m;
}

extern "C" void kernel_launch(void* const* d_in, const int* in_sizes, int n_in,
                              void* d_out, int out_size, void* d_ws, size_t ws_size,
                              hipStream_t stream)
{
    const float* x  = (const float*)d_in[0];
    const int*   ei = (const int*)d_in[1];
    const float* ea = (const float*)d_in[2];
    const float* W1 = (const float*)d_in[3];
    const float* b1 = (const float*)d_in[4];
    const float* W2 = (const float*)d_in[5];
    const float* b2 = (const float*)d_in[6];

    float* aggp = (float*)d_out;                          // [N,64]
    float* outp = aggp + (size_t)NNODES * 64;             // [E,64]

    // ws layout
    short*    xb   = (short*)d_ws;                        // 6,400,000 B bf16 x
    short*    wpk  = (short*)((char*)d_ws + 6400000);     //   114,688 B packed W1+W2
    unsigned* meta = (unsigned*)((char*)d_ws + 6514688);
    unsigned* cnt   = meta;                               // [50000]
    unsigned* cur   = meta + 50000;                       // [50000]
    unsigned* offs  = meta + 100000;                      // [50001]
    unsigned* bsum  = meta + 150016;                      // [49]
    unsigned* elist = meta + 150144;                      // [800000]  (ends 950144)
    unsigned* ob16  = meta + 950144;                      // [E,64] bf16 = 102.4 MB

    const size_t NEED = 6514688ULL + 950144ULL * 4ULL + 102400000ULL;  // ~112.7 MB
    const bool big = ws_size >= NEED;

    (void)hipMemsetAsync(cnt, 0, 100000 * sizeof(unsigned), stream);   // cnt + cur
    prep_all<<<6410, 256, 0, stream>>>(x, xb, W1, W2, wpk, ei, cnt);
    csr_scan1<<<49, 1024, 0, stream>>>(cnt, offs, bsum);
    csr_scan2<<<1, 64, 0, stream>>>(bsum);
    csr_scan3<<<49, 1024, 0, stream>>>(cnt, offs, bsum);
    csr_place<<<NEDGES / 256, 256, 0, stream>>>(ei, offs, cur, elist);
    if (big) {
        edgeconv_main<true><<<NBLK, 1024, 0, stream>>>(xb, ei, ea, wpk, b1, b2,
                                                       outp, ob16);
        agg_b16<<<(NNODES + 3) / 4, 256, 0, stream>>>(offs, elist, ob16, aggp);
    } else {
        edgeconv_main<false><<<NBLK, 1024, 0, stream>>>(xb, ei, ea, wpk, b1, b2,
                                                        outp, nullptr);
        agg_list<<<(NNODES + 3) / 4, 256, 0, stream>>>(offs, elist, outp, aggp);
    }
}

// Round 14
// 310.176 us; speedup vs baseline: 1.2860x; 1.1553x over previous
//
#include <hip/hip_runtime.h>
#include <hip/hip_bf16.h>
#include <math.h>

#define NNODES 50000
#define NEDGES 800000
#define CHUNKS (NEDGES / 32)     // 25000 chunks of 32 edges (original order)
#define NBLK 256
#define GWAVES (NBLK * 16)       // persistent waves

using short8 = __attribute__((ext_vector_type(8))) short;   // 8 bf16 = 4 VGPRs
using f32x4  = __attribute__((ext_vector_type(4))) float;
using f32x16 = __attribute__((ext_vector_type(16))) float;  // 32x32 MFMA acc
using u32x4  = __attribute__((ext_vector_type(4))) unsigned;

// fp32 -> bf16 RNE
__device__ __forceinline__ short f2b(float v) {
    return __builtin_bit_cast(short, __float2bfloat16(v));
}
// pack 2 fp32 -> 1 dword of 2 bf16 (lo = a)
__device__ __forceinline__ unsigned cvt2(float a, float b) {
    return (unsigned)(unsigned short)f2b(a) | ((unsigned)(unsigned short)f2b(b) << 16);
}

// ---- merged prep: x->bf16, W pack, CSR count ----
__global__ void prep_all(const float* __restrict__ x, short* __restrict__ xb,
                         const float* __restrict__ W1, const float* __restrict__ W2,
                         short* __restrict__ wpk, const int* __restrict__ ei,
                         unsigned* __restrict__ cnt)
{
    int b = blockIdx.x;
    if (b < 3125) {                       // x -> bf16 (800000 float4 groups)
        int i = b * 256 + threadIdx.x;
        float4 v = reinterpret_cast<const float4*>(x)[i];
        short4 o;
        o.x = f2b(v.x); o.y = f2b(v.y); o.z = f2b(v.z); o.w = f2b(v.w);
        reinterpret_cast<short4*>(xb)[i] = o;
    } else if (b < 6250) {                // CSR degree count
        int e = (b - 3125) * 256 + threadIdx.x;
        atomicAdd(&cnt[ei[e]], 1u);
    } else {                              // weight pack (32x32x16 A-frag order)
        int i = (b - 6250) * 256 + threadIdx.x;
        if (i < 40960) {                  // W1 [k<160][n<256]
            int k = i >> 8, n = i & 255;
            int lane = (n & 31) + (((k >> 3) & 1) << 5);
            wpk[(((n >> 5) * 10 + (k >> 4)) * 64 + lane) * 8 + (k & 7)] = f2b(W1[i]);
        }
        if (i < 16384) {                  // W2 [k<256][n<64]
            int k = i >> 6, n = i & 63;
            int lane = (n & 31) + (((k >> 3) & 1) << 5);
            wpk[40960 + (((n >> 5) * 16 + (k >> 4)) * 64 + lane) * 8 + (k & 7)] = f2b(W2[i]);
        }
    }
}

// ---- CSR scan/place (proven) ----
__global__ __launch_bounds__(1024)
void csr_scan1(const unsigned* __restrict__ cnt, unsigned* __restrict__ offs,
               unsigned* __restrict__ bsum) {
    __shared__ unsigned sbuf[1024];
    int t = threadIdx.x, i = blockIdx.x * 1024 + t;
    unsigned v = (i < NNODES) ? cnt[i] : 0u;
    sbuf[t] = v;
    __syncthreads();
    for (int off = 1; off < 1024; off <<= 1) {
        unsigned add = (t >= off) ? sbuf[t - off] : 0u;
        __syncthreads();
        sbuf[t] += add;
        __syncthreads();
    }
    if (i < NNODES) offs[i] = sbuf[t];
    if (t == 1023) bsum[blockIdx.x] = sbuf[1023];
}

__global__ void csr_scan2(unsigned* __restrict__ bsum) {
    int t = threadIdx.x;
    unsigned v = (t < 49) ? bsum[t] : 0u;
    unsigned orig = v;
    for (int off = 1; off < 64; off <<= 1) {
        unsigned n = __shfl_up(v, off, 64);
        if (t >= off) v += n;
    }
    if (t < 49) bsum[t] = v - orig;
}

__global__ __launch_bounds__(1024)
void csr_scan3(const unsigned* __restrict__ cnt, unsigned* __restrict__ offs,
               const unsigned* __restrict__ bsum) {
    int i = blockIdx.x * 1024 + threadIdx.x;
    if (i < NNODES)       offs[i] = offs[i] - cnt[i] + bsum[blockIdx.x];
    else if (i == NNODES) offs[i] = NEDGES;
}

__global__ void csr_place(const int* __restrict__ ei, const unsigned* __restrict__ offs,
                          unsigned* __restrict__ cur, unsigned* __restrict__ elist) {
    int e = blockIdx.x * 256 + threadIdx.x;
    if (e < NEDGES) {
        int r = ei[e];
        unsigned p = offs[r] + atomicAdd(&cur[r], 1u);
        elist[p] = (unsigned)e;
    }
}

// ---- main MLP: R8 structure; non-volatile permlane + t-loop unroll 2 ----
__global__ __launch_bounds__(1024)
void edgeconv_main(const short* __restrict__ xb, const int* __restrict__ ei,
                   const float* __restrict__ ea, const short* __restrict__ wpk,
                   const float* __restrict__ b1, const float* __restrict__ b2,
                   float* __restrict__ outbuf)
{
    __shared__ short wlds[57344];        // 112 KB: W1 frags (80K) + W2 frags (32K)

    for (int i = threadIdx.x; i < 7168; i += 1024)
        reinterpret_cast<short8*>(wlds)[i] = reinterpret_cast<const short8*>(wpk)[i];
    __syncthreads();                     // only block-wide barrier

    const short* w1s = wlds;
    const short* w2s = wlds + 40960;
    const int lane = threadIdx.x & 63;
    const int wave = threadIdx.x >> 6;
    const int l32 = lane & 31, hi = lane >> 5;
    const int gw = blockIdx.x * 16 + wave;

    // prime the index pipeline
    int r = 0, cc = 0;
    if (gw < CHUNKS) {
        int e0 = gw * 32 + l32;
        r  = ei[e0];
        cc = ei[NEDGES + e0];
    }

    for (int c = gw; c < CHUNKS; c += GWAVES) {
        const int e = c * 32 + l32;       // this chunk's edge (original order)

        // ---- prefetch next chunk's indices (coalesced, hidden under compute) ----
        int cn = c + GWAVES;
        int r_n = 0, cc_n = 0;
        if (cn < CHUNKS) {
            int e1 = cn * 32 + l32;
            r_n  = ei[e1];
            cc_n = ei[NEDGES + e1];
        }

        // ---- gather B-fragments: k = ks*16 + hi*8 + j ----
        short8 fx[10];
        #pragma unroll
        for (int ks = 0; ks < 4; ++ks)
            fx[ks] = *reinterpret_cast<const short8*>(xb + r * 64 + ks * 16 + hi * 8);
        #pragma unroll
        for (int ks = 0; ks < 4; ++ks)
            fx[4 + ks] = *reinterpret_cast<const short8*>(xb + cc * 64 + ks * 16 + hi * 8);
        #pragma unroll
        for (int ks = 0; ks < 2; ++ks) {
            const float4* p = reinterpret_cast<const float4*>(ea + (size_t)e * 32 + ks * 16 + hi * 8);
            float4 a = p[0], b = p[1];
            u32x4 uu;
            uu[0] = cvt2(a.x, a.y); uu[1] = cvt2(a.z, a.w);
            uu[2] = cvt2(b.x, b.y); uu[3] = cvt2(b.z, b.w);
            fx[8 + ks] = __builtin_bit_cast(short8, uu);
        }

        // ---- acc2 init = b2 ----
        f32x16 acc2[2];
        #pragma unroll
        for (int t2 = 0; t2 < 2; ++t2)
            #pragma unroll
            for (int g = 0; g < 4; ++g) {
                float4 bb = *reinterpret_cast<const float4*>(b2 + t2 * 32 + g * 8 + hi * 4);
                acc2[t2][g * 4 + 0] = bb.x; acc2[t2][g * 4 + 1] = bb.y;
                acc2[t2][g * 4 + 2] = bb.z; acc2[t2][g * 4 + 3] = bb.w;
            }

        // unroll 2: lets the scheduler interleave GEMM2(t) (indep acc2 chains)
        // with GEMM1(t+1)'s dependent chain — permlane asm is non-volatile so
        // nothing pins the order.
        #pragma unroll 2
        for (int t = 0; t < 8; ++t) {    // 8 H-tiles of 32 cols
            f32x16 acc1;
            #pragma unroll
            for (int g = 0; g < 4; ++g) {
                float4 bb = *reinterpret_cast<const float4*>(b1 + t * 32 + g * 8 + hi * 4);
                acc1[g * 4 + 0] = bb.x; acc1[g * 4 + 1] = bb.y;
                acc1[g * 4 + 2] = bb.z; acc1[g * 4 + 3] = bb.w;
            }
            #pragma unroll
            for (int ks = 0; ks < 10; ++ks) {
                short8 wf = *reinterpret_cast<const short8*>(
                    w1s + ((t * 10 + ks) * 64 + lane) * 8);
                acc1 = __builtin_amdgcn_mfma_f32_32x32x16_bf16(wf, fx[ks], acc1, 0, 0, 0);
            }
            // ---- ReLU + bf16 + permlane32_swap -> GEMM2 B-frags in-register ----
            #pragma unroll
            for (int ksl = 0; ksl < 2; ++ksl) {
                int q0 = ksl * 8;
                unsigned D0 = cvt2(fmaxf(acc1[q0 + 0], 0.f), fmaxf(acc1[q0 + 1], 0.f));
                unsigned D1 = cvt2(fmaxf(acc1[q0 + 2], 0.f), fmaxf(acc1[q0 + 3], 0.f));
                unsigned D2 = cvt2(fmaxf(acc1[q0 + 4], 0.f), fmaxf(acc1[q0 + 5], 0.f));
                unsigned D3 = cvt2(fmaxf(acc1[q0 + 6], 0.f), fmaxf(acc1[q0 + 7], 0.f));
                asm("v_permlane32_swap_b32 %0, %1" : "+v"(D0), "+v"(D2));
                asm("v_permlane32_swap_b32 %0, %1" : "+v"(D1), "+v"(D3));
                u32x4 bu; bu[0] = D0; bu[1] = D1; bu[2] = D2; bu[3] = D3;
                short8 hb = __builtin_bit_cast(short8, bu);

                int ks2 = t * 2 + ksl;
                short8 w20 = *reinterpret_cast<const short8*>(w2s + (ks2 * 64 + lane) * 8);
                short8 w21 = *reinterpret_cast<const short8*>(w2s + ((16 + ks2) * 64 + lane) * 8);
                acc2[0] = __builtin_amdgcn_mfma_f32_32x32x16_bf16(w20, hb, acc2[0], 0, 0, 0);
                acc2[1] = __builtin_amdgcn_mfma_f32_32x32x16_bf16(w21, hb, acc2[1], 0, 0, 0);
            }
        }

        // ---- epilogue: normal f32 out stores (L2-merged) ----
        #pragma unroll
        for (int t2 = 0; t2 < 2; ++t2)
            #pragma unroll
            for (int g = 0; g < 4; ++g) {
                f32x4 v;
                v[0] = acc2[t2][g * 4 + 0]; v[1] = acc2[t2][g * 4 + 1];
                v[2] = acc2[t2][g * 4 + 2]; v[3] = acc2[t2][g * 4 + 3];
                *reinterpret_cast<f32x4*>(outbuf + (size_t)e * 64 + t2 * 32 + g * 8 + hi * 4) = v;
            }

        r = r_n; cc = cc_n;
    }
}

// ---- aggregate: one wave per node, lane = column, 4-deep ILP max walk ----
__global__ __launch_bounds__(256)
void agg_list(const unsigned* __restrict__ offs, const unsigned* __restrict__ elist,
              const float* __restrict__ outbuf, float* __restrict__ agg)
{
    const int wave = threadIdx.x >> 6, lane = threadIdx.x & 63;
    const int node = blockIdx.x * 4 + wave;
    if (node >= NNODES) return;
    const unsigned s = offs[node], eend = offs[node + 1];
    float m0 = -INFINITY, m1 = -INFINITY, m2 = -INFINITY, m3 = -INFINITY;
    unsigned p = s;
    for (; p + 4 <= eend; p += 4) {
        float a = outbuf[(size_t)elist[p + 0] * 64 + lane];
        float b = outbuf[(size_t)elist[p + 1] * 64 + lane];
        float c = outbuf[(size_t)elist[p + 2] * 64 + lane];
        float d = outbuf[(size_t)elist[p + 3] * 64 + lane];
        m0 = fmaxf(m0, a); m1 = fmaxf(m1, b);
        m2 = fmaxf(m2, c); m3 = fmaxf(m3, d);
    }
    for (; p < eend; ++p) m0 = fmaxf(m0, outbuf[(size_t)elist[p] * 64 + lane]);
    float m = fmaxf(fmaxf(m0, m1), fmaxf(m2, m3));
    agg[(size_t)node * 64 + lane] = (s == eend) ? 0.0f : m;
}

extern "C" void kernel_launch(void* const* d_in, const int* in_sizes, int n_in,
                              void* d_out, int out_size, void* d_ws, size_t ws_size,
                              hipStream_t stream)
{
    const float* x  = (const float*)d_in[0];
    const int*   ei = (const int*)d_in[1];
    const float* ea = (const float*)d_in[2];
    const float* W1 = (const float*)d_in[3];
    const float* b1 = (const float*)d_in[4];
    const float* W2 = (const float*)d_in[5];
    const float* b2 = (const float*)d_in[6];

    float* aggp = (float*)d_out;                          // [N,64]
    float* outp = aggp + (size_t)NNODES * 64;             // [E,64]

    // ws layout (~10.3 MB, proven)
    short*    xb   = (short*)d_ws;                        // 6,400,000 B bf16 x
    short*    wpk  = (short*)((char*)d_ws + 6400000);     //   114,688 B packed W1+W2
    unsigned* meta = (unsigned*)((char*)d_ws + 6514688);
    unsigned* cnt   = meta;                               // [50000]
    unsigned* cur   = meta + 50000;                       // [50000]
    unsigned* offs  = meta + 100000;                      // [50001]
    unsigned* bsum  = meta + 150016;                      // [49]
    unsigned* elist = meta + 150144;                      // [800000]

    (void)hipMemsetAsync(cnt, 0, 100000 * sizeof(unsigned), stream);   // cnt + cur
    prep_all<<<6410, 256, 0, stream>>>(x, xb, W1, W2, wpk, ei, cnt);
    csr_scan1<<<49, 1024, 0, stream>>>(cnt, offs, bsum);
    csr_scan2<<<1, 64, 0, stream>>>(bsum);
    csr_scan3<<<49, 1024, 0, stream>>>(cnt, offs, bsum);
    csr_place<<<NEDGES / 256, 256, 0, stream>>>(ei, offs, cur, elist);
    edgeconv_main<<<NBLK, 1024, 0, stream>>>(xb, ei, ea, wpk, b1, b2, outp);
    agg_list<<<(NNODES + 3) / 4, 256, 0, stream>>>(offs, elist, outp, aggp);
}

// Round 15
// 289.967 us; speedup vs baseline: 1.3756x; 1.0697x over previous
//
#include <hip/hip_runtime.h>
#include <hip/hip_bf16.h>
#include <math.h>

#define NNODES 50000
#define NEDGES 800000
#define CHUNKS (NEDGES / 64)     // 12500 chunks of 64 edges (original order)
#define NBLK 256
#define GWAVES (NBLK * 8)        // 2048 persistent waves (512-thr blocks)

using short8 = __attribute__((ext_vector_type(8))) short;   // 8 bf16 = 4 VGPRs
using f32x4  = __attribute__((ext_vector_type(4))) float;
using f32x16 = __attribute__((ext_vector_type(16))) float;  // 32x32 MFMA acc
using u32x4  = __attribute__((ext_vector_type(4))) unsigned;

// fp32 -> bf16 RNE
__device__ __forceinline__ short f2b(float v) {
    return __builtin_bit_cast(short, __float2bfloat16(v));
}
// pack 2 fp32 -> 1 dword of 2 bf16 (lo = a)
__device__ __forceinline__ unsigned cvt2(float a, float b) {
    return (unsigned)(unsigned short)f2b(a) | ((unsigned)(unsigned short)f2b(b) << 16);
}

// ---- merged prep: x->bf16, W pack, CSR count ----
__global__ void prep_all(const float* __restrict__ x, short* __restrict__ xb,
                         const float* __restrict__ W1, const float* __restrict__ W2,
                         short* __restrict__ wpk, const int* __restrict__ ei,
                         unsigned* __restrict__ cnt)
{
    int b = blockIdx.x;
    if (b < 3125) {                       // x -> bf16 (800000 float4 groups)
        int i = b * 256 + threadIdx.x;
        float4 v = reinterpret_cast<const float4*>(x)[i];
        short4 o;
        o.x = f2b(v.x); o.y = f2b(v.y); o.z = f2b(v.z); o.w = f2b(v.w);
        reinterpret_cast<short4*>(xb)[i] = o;
    } else if (b < 6250) {                // CSR degree count
        int e = (b - 3125) * 256 + threadIdx.x;
        atomicAdd(&cnt[ei[e]], 1u);
    } else {                              // weight pack (32x32x16 A-frag order)
        int i = (b - 6250) * 256 + threadIdx.x;
        if (i < 40960) {                  // W1 [k<160][n<256]
            int k = i >> 8, n = i & 255;
            int lane = (n & 31) + (((k >> 3) & 1) << 5);
            wpk[(((n >> 5) * 10 + (k >> 4)) * 64 + lane) * 8 + (k & 7)] = f2b(W1[i]);
        }
        if (i < 16384) {                  // W2 [k<256][n<64]
            int k = i >> 6, n = i & 63;
            int lane = (n & 31) + (((k >> 3) & 1) << 5);
            wpk[40960 + (((n >> 5) * 16 + (k >> 4)) * 64 + lane) * 8 + (k & 7)] = f2b(W2[i]);
        }
    }
}

// ---- CSR scan/place (proven) ----
__global__ __launch_bounds__(1024)
void csr_scan1(const unsigned* __restrict__ cnt, unsigned* __restrict__ offs,
               unsigned* __restrict__ bsum) {
    __shared__ unsigned sbuf[1024];
    int t = threadIdx.x, i = blockIdx.x * 1024 + t;
    unsigned v = (i < NNODES) ? cnt[i] : 0u;
    sbuf[t] = v;
    __syncthreads();
    for (int off = 1; off < 1024; off <<= 1) {
        unsigned add = (t >= off) ? sbuf[t - off] : 0u;
        __syncthreads();
        sbuf[t] += add;
        __syncthreads();
    }
    if (i < NNODES) offs[i] = sbuf[t];
    if (t == 1023) bsum[blockIdx.x] = sbuf[1023];
}

__global__ void csr_scan2(unsigned* __restrict__ bsum) {
    int t = threadIdx.x;
    unsigned v = (t < 49) ? bsum[t] : 0u;
    unsigned orig = v;
    for (int off = 1; off < 64; off <<= 1) {
        unsigned n = __shfl_up(v, off, 64);
        if (t >= off) v += n;
    }
    if (t < 49) bsum[t] = v - orig;
}

__global__ __launch_bounds__(1024)
void csr_scan3(const unsigned* __restrict__ cnt, unsigned* __restrict__ offs,
               const unsigned* __restrict__ bsum) {
    int i = blockIdx.x * 1024 + threadIdx.x;
    if (i < NNODES)       offs[i] = offs[i] - cnt[i] + bsum[blockIdx.x];
    else if (i == NNODES) offs[i] = NEDGES;
}

__global__ void csr_place(const int* __restrict__ ei, const unsigned* __restrict__ offs,
                          unsigned* __restrict__ cur, unsigned* __restrict__ elist) {
    int e = blockIdx.x * 256 + threadIdx.x;
    if (e < NEDGES) {
        int r = ei[e];
        unsigned p = offs[r] + atomicAdd(&cur[r], 1u);
        elist[p] = (unsigned)e;
    }
}

// ---- main MLP: M=64/wave (2 edge groups), 512-thr blocks, 256-reg tier ----
// launch_bounds(512,2): 2 waves/SIMD min -> 256-reg budget, no spills for the
// ~226-reg live set (fx[2][10]=80V + acc1[2]=32A + acc2[2][2]=64A + addr).
// W1/W2 LDS reads amortized over 2x edges; GEMM1 has 2 indep MFMA chains.
__global__ __launch_bounds__(512, 2)
void edgeconv_main(const short* __restrict__ xb, const int* __restrict__ ei,
                   const float* __restrict__ ea, const short* __restrict__ wpk,
                   const float* __restrict__ b1, const float* __restrict__ b2,
                   float* __restrict__ outbuf)
{
    __shared__ short wlds[57344];        // 112 KB: W1 frags (80K) + W2 frags (32K)

    for (int i = threadIdx.x; i < 7168; i += 512)
        reinterpret_cast<short8*>(wlds)[i] = reinterpret_cast<const short8*>(wpk)[i];
    __syncthreads();                     // only block-wide barrier

    const short* w1s = wlds;
    const short* w2s = wlds + 40960;
    const int lane = threadIdx.x & 63;
    const int wave = threadIdx.x >> 6;
    const int l32 = lane & 31, hi = lane >> 5;
    const int gw = blockIdx.x * 8 + wave;

    // prime the index pipeline (2 edge groups)
    int r0 = 0, r1 = 0, c0 = 0, c1 = 0;
    {
        int ea0 = gw * 64 + l32, ea1 = gw * 64 + 32 + l32;
        r0 = ei[ea0]; c0 = ei[NEDGES + ea0];
        r1 = ei[ea1]; c1 = ei[NEDGES + ea1];
    }

    for (int c = gw; c < CHUNKS; c += GWAVES) {
        // ---- prefetch next chunk's indices ----
        int cn = c + GWAVES;
        int r0n = 0, r1n = 0, c0n = 0, c1n = 0;
        if (cn < CHUNKS) {
            int ea0 = cn * 64 + l32, ea1 = cn * 64 + 32 + l32;
            r0n = ei[ea0]; c0n = ei[NEDGES + ea0];
            r1n = ei[ea1]; c1n = ei[NEDGES + ea1];
        }

        // ---- gather B-fragments for both groups: k = ks*16 + hi*8 + j ----
        short8 fx[2][10];
        #pragma unroll
        for (int g = 0; g < 2; ++g) {
            const int rr = g ? r1 : r0, cg = g ? c1 : c0;
            const int e = c * 64 + g * 32 + l32;
            #pragma unroll
            for (int ks = 0; ks < 4; ++ks)
                fx[g][ks] = *reinterpret_cast<const short8*>(xb + rr * 64 + ks * 16 + hi * 8);
            #pragma unroll
            for (int ks = 0; ks < 4; ++ks)
                fx[g][4 + ks] = *reinterpret_cast<const short8*>(xb + cg * 64 + ks * 16 + hi * 8);
            #pragma unroll
            for (int ks = 0; ks < 2; ++ks) {
                const float4* p = reinterpret_cast<const float4*>(ea + (size_t)e * 32 + ks * 16 + hi * 8);
                float4 a = p[0], b = p[1];
                u32x4 uu;
                uu[0] = cvt2(a.x, a.y); uu[1] = cvt2(a.z, a.w);
                uu[2] = cvt2(b.x, b.y); uu[3] = cvt2(b.z, b.w);
                fx[g][8 + ks] = __builtin_bit_cast(short8, uu);
            }
        }

        // ---- acc2 init = b2 ----
        f32x16 acc2[2][2];   // [t2][g]
        #pragma unroll
        for (int t2 = 0; t2 < 2; ++t2)
            #pragma unroll
            for (int gg = 0; gg < 4; ++gg) {
                float4 bb = *reinterpret_cast<const float4*>(b2 + t2 * 32 + gg * 8 + hi * 4);
                #pragma unroll
                for (int g = 0; g < 2; ++g) {
                    acc2[t2][g][gg * 4 + 0] = bb.x; acc2[t2][g][gg * 4 + 1] = bb.y;
                    acc2[t2][g][gg * 4 + 2] = bb.z; acc2[t2][g][gg * 4 + 3] = bb.w;
                }
            }

        #pragma unroll 1
        for (int t = 0; t < 8; ++t) {    // 8 H-tiles of 32 cols
            // ---- GEMM1: one W1 frag feeds 2 independent chains ----
            f32x16 acc1[2];
            #pragma unroll
            for (int gg = 0; gg < 4; ++gg) {
                float4 bb = *reinterpret_cast<const float4*>(b1 + t * 32 + gg * 8 + hi * 4);
                #pragma unroll
                for (int g = 0; g < 2; ++g) {
                    acc1[g][gg * 4 + 0] = bb.x; acc1[g][gg * 4 + 1] = bb.y;
                    acc1[g][gg * 4 + 2] = bb.z; acc1[g][gg * 4 + 3] = bb.w;
                }
            }
            #pragma unroll
            for (int ks = 0; ks < 10; ++ks) {
                short8 wf = *reinterpret_cast<const short8*>(
                    w1s + ((t * 10 + ks) * 64 + lane) * 8);
                acc1[0] = __builtin_amdgcn_mfma_f32_32x32x16_bf16(wf, fx[0][ks], acc1[0], 0, 0, 0);
                acc1[1] = __builtin_amdgcn_mfma_f32_32x32x16_bf16(wf, fx[1][ks], acc1[1], 0, 0, 0);
            }
            // ---- ReLU + bf16 + permlane -> GEMM2 (W2 frags shared by groups) ----
            #pragma unroll
            for (int ksl = 0; ksl < 2; ++ksl) {
                int ks2 = t * 2 + ksl;
                short8 w20 = *reinterpret_cast<const short8*>(w2s + (ks2 * 64 + lane) * 8);
                short8 w21 = *reinterpret_cast<const short8*>(w2s + ((16 + ks2) * 64 + lane) * 8);
                #pragma unroll
                for (int g = 0; g < 2; ++g) {
                    int q0 = ksl * 8;
                    unsigned D0 = cvt2(fmaxf(acc1[g][q0 + 0], 0.f), fmaxf(acc1[g][q0 + 1], 0.f));
                    unsigned D1 = cvt2(fmaxf(acc1[g][q0 + 2], 0.f), fmaxf(acc1[g][q0 + 3], 0.f));
                    unsigned D2 = cvt2(fmaxf(acc1[g][q0 + 4], 0.f), fmaxf(acc1[g][q0 + 5], 0.f));
                    unsigned D3 = cvt2(fmaxf(acc1[g][q0 + 6], 0.f), fmaxf(acc1[g][q0 + 7], 0.f));
                    asm("v_permlane32_swap_b32 %0, %1" : "+v"(D0), "+v"(D2));
                    asm("v_permlane32_swap_b32 %0, %1" : "+v"(D1), "+v"(D3));
                    u32x4 bu; bu[0] = D0; bu[1] = D1; bu[2] = D2; bu[3] = D3;
                    short8 hb = __builtin_bit_cast(short8, bu);
                    acc2[0][g] = __builtin_amdgcn_mfma_f32_32x32x16_bf16(w20, hb, acc2[0][g], 0, 0, 0);
                    acc2[1][g] = __builtin_amdgcn_mfma_f32_32x32x16_bf16(w21, hb, acc2[1][g], 0, 0, 0);
                }
            }
        }

        // ---- epilogue: normal f32 out stores ----
        #pragma unroll
        for (int g = 0; g < 2; ++g) {
            const int e = c * 64 + g * 32 + l32;
            #pragma unroll
            for (int t2 = 0; t2 < 2; ++t2)
                #pragma unroll
                for (int gg = 0; gg < 4; ++gg) {
                    f32x4 v;
                    v[0] = acc2[t2][g][gg * 4 + 0]; v[1] = acc2[t2][g][gg * 4 + 1];
                    v[2] = acc2[t2][g][gg * 4 + 2]; v[3] = acc2[t2][g][gg * 4 + 3];
                    *reinterpret_cast<f32x4*>(outbuf + (size_t)e * 64 + t2 * 32 + gg * 8 + hi * 4) = v;
                }
        }

        r0 = r0n; r1 = r1n; c0 = c0n; c1 = c1n;
    }
}

// ---- aggregate: one wave per node, lane = column, 8-deep ILP max walk ----
__global__ __launch_bounds__(256)
void agg_list(const unsigned* __restrict__ offs, const unsigned* __restrict__ elist,
              const float* __restrict__ outbuf, float* __restrict__ agg)
{
    const int wave = threadIdx.x >> 6, lane = threadIdx.x & 63;
    const int node = blockIdx.x * 4 + wave;
    if (node >= NNODES) return;
    const unsigned s = offs[node], eend = offs[node + 1];
    float m0 = -INFINITY, m1 = -INFINITY, m2 = -INFINITY, m3 = -INFINITY;
    float m4 = -INFINITY, m5 = -INFINITY, m6 = -INFINITY, m7 = -INFINITY;
    unsigned p = s;
    for (; p + 8 <= eend; p += 8) {
        float a = outbuf[(size_t)elist[p + 0] * 64 + lane];
        float b = outbuf[(size_t)elist[p + 1] * 64 + lane];
        float c = outbuf[(size_t)elist[p + 2] * 64 + lane];
        float d = outbuf[(size_t)elist[p + 3] * 64 + lane];
        float e = outbuf[(size_t)elist[p + 4] * 64 + lane];
        float f = outbuf[(size_t)elist[p + 5] * 64 + lane];
        float g = outbuf[(size_t)elist[p + 6] * 64 + lane];
        float h = outbuf[(size_t)elist[p + 7] * 64 + lane];
        m0 = fmaxf(m0, a); m1 = fmaxf(m1, b); m2 = fmaxf(m2, c); m3 = fmaxf(m3, d);
        m4 = fmaxf(m4, e); m5 = fmaxf(m5, f); m6 = fmaxf(m6, g); m7 = fmaxf(m7, h);
    }
    for (; p < eend; ++p) m0 = fmaxf(m0, outbuf[(size_t)elist[p] * 64 + lane]);
    float m = fmaxf(fmaxf(fmaxf(m0, m1), fmaxf(m2, m3)),
                    fmaxf(fmaxf(m4, m5), fmaxf(m6, m7)));
    agg[(size_t)node * 64 + lane] = (s == eend) ? 0.0f : m;
}

extern "C" void kernel_launch(void* const* d_in, const int* in_sizes, int n_in,
                              void* d_out, int out_size, void* d_ws, size_t ws_size,
                              hipStream_t stream)
{
    const float* x  = (const float*)d_in[0];
    const int*   ei = (const int*)d_in[1];
    const float* ea = (const float*)d_in[2];
    const float* W1 = (const float*)d_in[3];
    const float* b1 = (const float*)d_in[4];
    const float* W2 = (const float*)d_in[5];
    const float* b2 = (const float*)d_in[6];

    float* aggp = (float*)d_out;                          // [N,64]
    float* outp = aggp + (size_t)NNODES * 64;             // [E,64]

    // ws layout (~10.3 MB, proven)
    short*    xb   = (short*)d_ws;                        // 6,400,000 B bf16 x
    short*    wpk  = (short*)((char*)d_ws + 6400000);     //   114,688 B packed W1+W2
    unsigned* meta = (unsigned*)((char*)d_ws + 6514688);
    unsigned* cnt   = meta;                               // [50000]
    unsigned* cur   = meta + 50000;                       // [50000]
    unsigned* offs  = meta + 100000;                      // [50001]
    unsigned* bsum  = meta + 150016;                      // [49]
    unsigned* elist = meta + 150144;                      // [800000]

    (void)hipMemsetAsync(cnt, 0, 100000 * sizeof(unsigned), stream);   // cnt + cur
    prep_all<<<6410, 256, 0, stream>>>(x, xb, W1, W2, wpk, ei, cnt);
    csr_scan1<<<49, 1024, 0, stream>>>(cnt, offs, bsum);
    csr_scan2<<<1, 64, 0, stream>>>(bsum);
    csr_scan3<<<49, 1024, 0, stream>>>(cnt, offs, bsum);
    csr_place<<<NEDGES / 256, 256, 0, stream>>>(ei, offs, cur, elist);
    edgeconv_main<<<NBLK, 512, 0, stream>>>(xb, ei, ea, wpk, b1, b2, outp);
    agg_list<<<(NNODES + 3) / 4, 256, 0, stream>>>(offs, elist, outp, aggp);
}